// Round 9
// baseline (232.072 us; speedup 1.0000x reference)
//
#include <hip/hip_runtime.h>

typedef __bf16 bf16x8 __attribute__((ext_vector_type(8)));
typedef float f32x4 __attribute__((ext_vector_type(4)));
typedef float f32x16 __attribute__((ext_vector_type(16)));
typedef unsigned short u16x8 __attribute__((ext_vector_type(8)));
typedef unsigned int u32x4 __attribute__((ext_vector_type(4)));
typedef unsigned int u32x2v __attribute__((ext_vector_type(2)));

#define S_LEN 2048
#define NHEAD 16
#define HDIM  64
#define EMB   1024

__device__ __forceinline__ ushort f2b(float v) {
  union { float f; unsigned u; } x; x.f = v;
  unsigned r = (x.u + 0x7fffu + ((x.u >> 16) & 1u)) >> 16;
  return (ushort)r;
}

// pack two f32 -> u32 of 2 bf16 (truncation)
__device__ __forceinline__ unsigned pk2(float lo, float hi) {
  union { float f; unsigned u; } a, b; a.f = lo; b.f = hi;
  return (b.u & 0xffff0000u) | (a.u >> 16);
}

// async global->LDS, 16B per lane; LDS dest = wave-uniform base + lane*16
typedef const __attribute__((address_space(1))) unsigned int* gp1_t;
typedef __attribute__((address_space(3))) unsigned int* lp3_t;
__device__ __forceinline__ void gld16(const ushort* g, const ushort* l) {
  __builtin_amdgcn_global_load_lds((gp1_t)(unsigned long long)(uintptr_t)g,
                                   (lp3_t)(unsigned int)(uintptr_t)l, 16, 0, 0);
}

__device__ __forceinline__ void barf() {
  asm volatile("" ::: "memory");
  __builtin_amdgcn_s_barrier();
  asm volatile("" ::: "memory");
}

// ---------- fused prep: cast x -> bf16 (z==4) + transpose/cast weights (z<4) ----------
__global__ __launch_bounds__(256) void prep_kernel(
    const float* __restrict__ x, const float* __restrict__ W0,
    const float* __restrict__ W1, const float* __restrict__ W2,
    const float* __restrict__ W3, ushort* __restrict__ xb,
    ushort* __restrict__ Wt0, ushort* __restrict__ Wt1,
    ushort* __restrict__ Wt2, ushort* __restrict__ Wt3, float scale0) {
  const int z = blockIdx.z;
  if (z == 4) {  // x cast: 1024 blocks x 8192 floats
    size_t base = ((size_t)(blockIdx.y * 32 + blockIdx.x)) * 8192 + threadIdx.x * 4;
#pragma unroll
    for (int i = 0; i < 8; ++i) {
      float4 v = *(const float4*)(x + base + i * 1024);
      ushort4 o;
      o.x = f2b(v.x); o.y = f2b(v.y); o.z = f2b(v.z); o.w = f2b(v.w);
      *(ushort4*)(xb + base + i * 1024) = o;
    }
    return;
  }
  __shared__ float t[32][33];
  const float* W = z == 0 ? W0 : (z == 1 ? W1 : (z == 2 ? W2 : W3));
  ushort* Wt = z == 0 ? Wt0 : (z == 1 ? Wt1 : (z == 2 ? Wt2 : Wt3));
  const float scale = z == 0 ? scale0 : 1.0f;
  int k0 = blockIdx.x * 32, n0 = blockIdx.y * 32;
  int c = threadIdx.x & 31, r0 = threadIdx.x >> 5;
#pragma unroll
  for (int i = 0; i < 4; ++i) {
    int r = r0 + i * 8;
    t[r][c] = W[(size_t)(k0 + r) * EMB + n0 + c];
  }
  __syncthreads();
#pragma unroll
  for (int i = 0; i < 4; ++i) {
    int r = r0 + i * 8;
    Wt[(size_t)(n0 + r) * EMB + k0 + c] = f2b(t[c][r] * scale);
  }
}

// ---------------- GEMM 256x256 (QKV): balanced-pipe geometry ----------------
// C[M,N] = A[M,K] * Bt[N,K]^T.  256x256 tile, BK=64, 8 waves (2M x 4N,
// per-wave 128x64, acc[8][4]), 512 threads, grid 32x12 = 384 blocks.
// Why: at 128x256 the LDS pipe (reads 128KB + writes 48KB = 1408 cyc/K-tile)
// exceeds MFMA (1030 cyc) -> structure is LDS-bound at ~37% MfmaUtil.  At
// 256x256 per-wave 128x64: reads 192KB + writes 64KB = 2048 cyc vs MFMA
// 2060 cyc -> balanced.  2-buffer LDS (128KiB), ALL 8 staging loads issued
// at tile start (vs ~2300-cyc tile, L2 latency+delivery ~1400 -> end-of-tile
// vmcnt(0) drain mostly covered).  One barrier/tile, vmcnt(0)+lgkmcnt(0)
// BEFORE it (per-wave wait + barrier = cross-wave guarantee).  Swizzle:
// v5's proven 128B-row chunk^=(row&7), pre-swizzled global source + linear
// gld_lds dest (rule #21).  Epilogue: Q,K [b,h,s,d] bf16; V^T [b,h,d,s].
__global__ __launch_bounds__(512, 2) void gemm256_kernel(
    const ushort* __restrict__ A, const ushort* __restrict__ Bt,
    ushort* __restrict__ outQ, ushort* __restrict__ outK,
    ushort* __restrict__ outVt) {
  // A bufs: 2 x [256][64] ushort at 0       (buf b at b*16384)
  // B bufs: 2 x [256][64] ushort at 32768   (buf b at 32768 + b*16384)
  __shared__ ushort lds2[65536];  // 128 KiB
  const int tid = threadIdx.x;
  const int wave = tid >> 6, lane = tid & 63, ln = lane & 15, quad = lane >> 4;
  const int wm = wave >> 2, wn = wave & 3;
  const long m0 = (long)blockIdx.x * 256, n0 = (long)blockIdx.y * 256;
  constexpr int K = EMB, KT = K / 64;  // 16 K-tiles

  // staging: chunk j = ld*512 + tid of a [256][64u] buf: row = ld*64 + (tid>>3),
  // c = tid&7; LDS(row,c) holds data(row, c ^ (row&7)); (row&7)==((tid>>3)&7).
  const int srow = tid >> 3;                         // 0..63 (+64 per ld)
  const int scol = ((tid & 7) ^ (srow & 7)) * 8;     // swizzled ushort col
  const ushort* srcA = A + (m0 + srow) * (long)K + scol;
  const ushort* srcB = Bt + (n0 + srow) * (long)K + scol;

#define STG_A(t, b)                                                            \
  do {                                                                         \
    _Pragma("unroll") for (int ld = 0; ld < 4; ++ld)                           \
        gld16(srcA + (t) * 64 + ld * 64 * K,                                   \
              lds2 + (b) * 16384 + ld * 4096 + tid * 8);                       \
  } while (0)
#define STG_B(t, b)                                                            \
  do {                                                                         \
    _Pragma("unroll") for (int ld = 0; ld < 4; ++ld)                           \
        gld16(srcB + (t) * 64 + ld * 64 * K,                                   \
              lds2 + 32768 + (b) * 16384 + ld * 4096 + tid * 8);               \
  } while (0)

  const int sw = (ln & 7) * 8;

#define RD_A8(F, kk, b)                                                        \
  do {                                                                         \
    const ushort* p_ = lds2 + (b) * 16384 + (wm * 128 + ln) * 64 +             \
                       (((kk) * 32 + quad * 8) ^ sw);                          \
    _Pragma("unroll") for (int m_ = 0; m_ < 8; ++m_)                           \
        F[m_] = *(const bf16x8*)(p_ + m_ * 1024);                              \
  } while (0)
#define RD_B4(F, kk, b)                                                        \
  do {                                                                         \
    const ushort* p_ = lds2 + 32768 + (b) * 16384 + (wn * 64 + ln) * 64 +      \
                       (((kk) * 32 + quad * 8) ^ sw);                          \
    _Pragma("unroll") for (int n_ = 0; n_ < 4; ++n_)                           \
        F[n_] = *(const bf16x8*)(p_ + n_ * 1024);                              \
  } while (0)

#define MM32(AF, BF)                                                           \
  do {                                                                         \
    __builtin_amdgcn_s_setprio(1);                                             \
    _Pragma("unroll") for (int mt = 0; mt < 8; ++mt)                           \
        _Pragma("unroll") for (int nt = 0; nt < 4; ++nt)                       \
            acc[mt][nt] = __builtin_amdgcn_mfma_f32_16x16x32_bf16(             \
                AF[mt], BF[nt], acc[mt][nt], 0, 0, 0);                         \
    __builtin_amdgcn_s_setprio(0);                                             \
  } while (0)

  f32x4 acc[8][4] = {};
  bf16x8 afP[8], bfP[4], afN[8], bfN[4];

  // prologue: stage tile 0, drain, barrier
  STG_A(0, 0); STG_B(0, 0);
  asm volatile("s_waitcnt vmcnt(0)" ::: "memory");
  barf();

  for (int kt = 0; kt < KT; ++kt) {
    const int bb = kt & 1;
    if (kt + 1 < KT) { STG_A(kt + 1, bb ^ 1); STG_B(kt + 1, bb ^ 1); }
    RD_A8(afP, 0, bb); RD_B4(bfP, 0, bb);
    MM32(afP, bfP);
    RD_A8(afN, 1, bb); RD_B4(bfN, 1, bb);
    MM32(afN, bfN);
    if (kt + 1 < KT) {
      asm volatile("s_waitcnt vmcnt(0) lgkmcnt(0)" ::: "memory");
      barf();
    }
  }

  // ---- epilogue: Q/K [b,h,s,d]; V transposed [b,h,d,s] ----
  const int sel = (int)(n0 >> 10);  // block-uniform (256 | 1024)
  if (sel == 2) {
#pragma unroll
    for (int mt = 0; mt < 8; ++mt) {
      const long mbase = m0 + wm * 128 + mt * 16 + quad * 4;
      const long bb2 = mbase >> 11, s = mbase & 2047;
#pragma unroll
      for (int nt = 0; nt < 4; ++nt) {
        const int nn = (int)((n0 & 1023) + wn * 64 + nt * 16 + ln);
        const int h = nn >> 6, d = nn & 63;
        uint2 val;
        val.x = (unsigned)f2b(acc[mt][nt][0]) | ((unsigned)f2b(acc[mt][nt][1]) << 16);
        val.y = (unsigned)f2b(acc[mt][nt][2]) | ((unsigned)f2b(acc[mt][nt][3]) << 16);
        *(uint2*)(outVt + (((bb2 * NHEAD + h) * (long)HDIM + d) * S_LEN) + s) = val;
      }
    }
  } else {
    ushort* dst = sel == 0 ? outQ : outK;
#pragma unroll
    for (int mt = 0; mt < 8; ++mt) {
#pragma unroll
      for (int nt = 0; nt < 4; ++nt) {
        const int nn = (int)((n0 & 1023) + wn * 64 + nt * 16 + ln);
        const int h = nn >> 6, d = nn & 63;
#pragma unroll
        for (int r = 0; r < 4; ++r) {
          const long m = m0 + wm * 128 + mt * 16 + quad * 4 + r;
          const long bb2 = m >> 11, s = m & 2047;
          dst[(((bb2 * NHEAD + h) * S_LEN) + s) * HDIM + d] = f2b(acc[mt][nt][r]);
        }
      }
    }
  }
#undef MM32
#undef RD_B4
#undef RD_A8
#undef STG_B
#undef STG_A
}

// ---------------- GEMM v5 128x256 (out-proj only; unchanged, passing) ----------------
template <int EPI>
__global__ __launch_bounds__(512, 2) void gemm8_kernel(
    const ushort* __restrict__ A, const ushort* __restrict__ Bt,
    float* __restrict__ outF, const float* __restrict__ bias) {
  __shared__ ushort lds8[73728];  // 144 KiB
  const int tid = threadIdx.x;
  const int wave = tid >> 6, lane = tid & 63, ln = lane & 15, quad = lane >> 4;
  const int wm = wave >> 2, wn = wave & 3;
  const long m0 = (long)blockIdx.x * 128, n0 = (long)blockIdx.y * 256;
  constexpr int K = EMB, KT = K / 64;  // 16 K-tiles

  const int srow = tid >> 3;
  const int scol = ((tid & 7) ^ (srow & 7)) * 8;
  const ushort* srcA = A + (m0 + srow) * (long)K + scol;
  const ushort* srcB = Bt + (n0 + srow) * (long)K + scol;

#define STG_A(t, s)                                                            \
  do {                                                                         \
    gld16(srcA + (t) * 64,               lds8 + (s) * 8192 + tid * 8);         \
    gld16(srcA + (t) * 64 + 64 * K,      lds8 + (s) * 8192 + 4096 + tid * 8);  \
  } while (0)
#define STG_B(t, s)                                                            \
  do {                                                                         \
    gld16(srcB + (t) * 64,               lds8 + 24576 + (s) * 16384 + tid * 8);         \
    gld16(srcB + (t) * 64 + 64 * K,      lds8 + 24576 + (s) * 16384 + 4096 + tid * 8);  \
    gld16(srcB + (t) * 64 + 128 * K,     lds8 + 24576 + (s) * 16384 + 8192 + tid * 8);  \
    gld16(srcB + (t) * 64 + 192 * K,     lds8 + 24576 + (s) * 16384 + 12288 + tid * 8); \
  } while (0)

  const int sw = (ln & 7) * 8;

#define RD_A(F, kk, s)                                                         \
  do {                                                                         \
    const ushort* p_ = lds8 + (s) * 8192 + (wm * 64 + ln) * 64 +               \
                       (((kk) * 32 + quad * 8) ^ sw);                          \
    F[0] = *(const bf16x8*)p_;                                                 \
    F[1] = *(const bf16x8*)(p_ + 1024);                                        \
    F[2] = *(const bf16x8*)(p_ + 2048);                                        \
    F[3] = *(const bf16x8*)(p_ + 3072);                                        \
  } while (0)
#define RD_B(F, kk, s)                                                         \
  do {                                                                         \
    const ushort* p_ = lds8 + 24576 + (s) * 16384 + (wn * 64 + ln) * 64 +      \
                       (((kk) * 32 + quad * 8) ^ sw);                          \
    F[0] = *(const bf16x8*)p_;                                                 \
    F[1] = *(const bf16x8*)(p_ + 1024);                                        \
    F[2] = *(const bf16x8*)(p_ + 2048);                                        \
    F[3] = *(const bf16x8*)(p_ + 3072);                                        \
  } while (0)

#define MM16(AF, BF)                                                           \
  do {                                                                         \
    __builtin_amdgcn_s_setprio(1);                                             \
    _Pragma("unroll") for (int mt = 0; mt < 4; ++mt)                           \
        _Pragma("unroll") for (int nt = 0; nt < 4; ++nt)                       \
            acc[mt][nt] = __builtin_amdgcn_mfma_f32_16x16x32_bf16(             \
                AF[mt], BF[nt], acc[mt][nt], 0, 0, 0);                         \
    __builtin_amdgcn_s_setprio(0);                                             \
  } while (0)

  f32x4 acc[4][4] = {};
  bf16x8 afP[4], bfP[4], afN[4], bfN[4];

  STG_A(0, 0); STG_B(0, 0);
  STG_A(1, 1); STG_B(1, 1);
  asm volatile("s_waitcnt vmcnt(6)" ::: "memory");
  barf();
  RD_A(afP, 0, 0); RD_B(bfP, 0, 0);

#define TILE_FULL(t, s, s1, s2)                                                \
  do {                                                                         \
    STG_A((t) + 2, s2);                                                        \
    RD_A(afN, 1, s); RD_B(bfN, 1, s);                                          \
    MM16(afP, bfP);                                                            \
    STG_B((t) + 2, s2);                                                        \
    asm volatile("s_waitcnt vmcnt(6) lgkmcnt(0)" ::: "memory");                \
    barf();                                                                    \
    RD_A(afP, 0, s1); RD_B(bfP, 0, s1);                                        \
    MM16(afN, bfN);                                                            \
  } while (0)

  for (int th = 0; th < 12; th += 3) {
    TILE_FULL(th, 0, 1, 2);
    TILE_FULL(th + 1, 1, 2, 0);
    TILE_FULL(th + 2, 2, 0, 1);
  }
  TILE_FULL(12, 0, 1, 2);
  TILE_FULL(13, 1, 2, 0);
  RD_A(afN, 1, 2); RD_B(bfN, 1, 2);
  MM16(afP, bfP);
  asm volatile("s_waitcnt vmcnt(0) lgkmcnt(0)" ::: "memory");
  barf();
  RD_A(afP, 0, 0); RD_B(bfP, 0, 0);
  MM16(afN, bfN);
  RD_A(afN, 1, 0); RD_B(bfN, 1, 0);
  MM16(afP, bfP);
  MM16(afN, bfN);

#pragma unroll
  for (int mt = 0; mt < 4; ++mt) {
#pragma unroll
    for (int nt = 0; nt < 4; ++nt) {
      const long n = n0 + wn * 64 + nt * 16 + ln;
      const float bv = bias[n];
#pragma unroll
      for (int r = 0; r < 4; ++r) {
        const long m = m0 + wm * 64 + mt * 16 + quad * 4 + r;
        outF[m * (long)EMB + n] = acc[mt][nt][r] + bv;
      }
    }
  }
#undef TILE_FULL
#undef MM16
#undef RD_B
#undef RD_A
#undef STG_B
#undef STG_A
}

// ---------------- flash attention, v8 (unchanged, passing) ----------------
__global__ __launch_bounds__(256, 3) void attn_kernel(const ushort* __restrict__ Q,
                                                      const ushort* __restrict__ Kg,
                                                      const ushort* __restrict__ Vt,
                                                      ushort* __restrict__ Y) {
  __shared__ alignas(16) ushort Ks[3][4096];  // [slot][key 64][d 64] swizzled
  __shared__ alignas(16) ushort Vs[3][4096];  // [slot][d 64][key 64] swizzled
  const int tid = threadIdx.x;
  const int wave = tid >> 6, lane = tid & 63;
  const int l31 = lane & 31, hi = lane >> 5;
  const int bh = blockIdx.x;
  const int qb = 15 - (int)blockIdx.y;  // LPT: longest q-blocks first
  const int q0 = qb * 128;
  const size_t base = (size_t)bh * S_LEN * HDIM;
  const int ntiles = 2 * qb + 2;

  const u16x8 ob = {0x3F80, 0x3F80, 0x3F80, 0x3F80, 0x3F80, 0x3F80, 0x3F80, 0x3F80};
  const bf16x8 ones = __builtin_bit_cast(bf16x8, ob);

  bf16x8 qf[4];
#pragma unroll
  for (int dsub = 0; dsub < 4; ++dsub)
    qf[dsub] = *(const bf16x8*)(Q + base + (size_t)(q0 + wave * 32 + l31) * HDIM +
                                dsub * 16 + hi * 8);

  f32x16 acc0 = {}, acc1 = {}, accl = {};

  const int srow = tid >> 3;                        // 0..31
  const int scc  = ((tid & 7) ^ (srow & 7)) * 8;    // swizzled ushort col
  const ushort* KgS = Kg + base + (size_t)srow * HDIM + scc;
  const ushort* VgS = Vt + base + (size_t)srow * S_LEN + scc;

#define STAGE(t, s)                                                            \
  do {                                                                         \
    const size_t kk_ = (size_t)(t) * 64;                                       \
    gld16(KgS + kk_ * HDIM,               &Ks[s][0] + tid * 8);                \
    gld16(KgS + (kk_ + 32) * HDIM,        &Ks[s][0] + 2048 + tid * 8);         \
    gld16(VgS + kk_,                      &Vs[s][0] + tid * 8);                \
    gld16(VgS + 32 * (size_t)S_LEN + kk_, &Vs[s][0] + 2048 + tid * 8);         \
  } while (0)

  STAGE(0, 0);
  STAGE(1, 1);
  asm volatile("s_waitcnt vmcnt(4)" ::: "memory");
  barf();

  const int swL = (lane & 7) * 8;   // K/V read swizzle (row&7 == lane&7)
  const int qbase = q0 + wave * 32;
  int sc = 0, sn = 1, ss = 2;       // ring slots: current / next / stage(t+2)

  for (int kt = 0; kt < ntiles; ++kt) {
    const int k0 = kt * 64;
    const bool do_stage = (kt + 2 < ntiles);
    if (do_stage) STAGE(kt + 2, ss);

    const ushort* Kc = &Ks[sc][0];
    const ushort* Vc = &Vs[sc][0];

    if (k0 < qbase + 32) {
      f32x16 sT0 = {}, sT1 = {};
      __builtin_amdgcn_s_setprio(1);
#pragma unroll
      for (int dsub = 0; dsub < 4; ++dsub) {
        const int c = (dsub * 16 + hi * 8) ^ swL;
        bf16x8 kf0 = *(const bf16x8*)(Kc + l31 * 64 + c);
        bf16x8 kf1 = *(const bf16x8*)(Kc + (32 + l31) * 64 + c);
        sT0 = __builtin_amdgcn_mfma_f32_32x32x16_bf16(kf0, qf[dsub], sT0, 0, 0, 0);
        sT1 = __builtin_amdgcn_mfma_f32_32x32x16_bf16(kf1, qf[dsub], sT1, 0, 0, 0);
      }
      __builtin_amdgcn_s_setprio(0);

      if (k0 + 63 > qbase) {  // diagonal region: causal mask
        const int rowq = qbase + l31;
#pragma unroll
        for (int r = 0; r < 16; ++r) {
          const int key = k0 + ((r & 3) + 8 * (r >> 2)) + 4 * hi;
          if (key > rowq) sT0[r] = -3.0e38f;
          if (key + 32 > rowq) sT1[r] = -3.0e38f;
        }
      }

      unsigned pw0[8], pw1[8];
#pragma unroll
      for (int i = 0; i < 8; ++i) {
        pw0[i] = pk2(__builtin_amdgcn_exp2f(sT0[2 * i]),
                     __builtin_amdgcn_exp2f(sT0[2 * i + 1]));
        pw1[i] = pk2(__builtin_amdgcn_exp2f(sT1[2 * i]),
                     __builtin_amdgcn_exp2f(sT1[2 * i + 1]));
      }

#define KEYBLK(PW, KSQ0)                                                       \
  do {                                                                         \
    u32x2v r02 = __builtin_amdgcn_permlane32_swap(PW[0], PW[2], false, false); \
    u32x2v r13 = __builtin_amdgcn_permlane32_swap(PW[1], PW[3], false, false); \
    u32x2v r46 = __builtin_amdgcn_permlane32_swap(PW[4], PW[6], false, false); \
    u32x2v r57 = __builtin_amdgcn_permlane32_swap(PW[5], PW[7], false, false); \
    u32x4 fwA, fwB;                                                            \
    fwA[0] = r02[0]; fwA[1] = r13[0]; fwA[2] = r02[1]; fwA[3] = r13[1];        \
    fwB[0] = r46[0]; fwB[1] = r57[0]; fwB[2] = r46[1]; fwB[3] = r57[1];        \
    bf16x8 paA = __builtin_bit_cast(bf16x8, fwA);                              \
    bf16x8 paB = __builtin_bit_cast(bf16x8, fwB);                              \
    __builtin_amdgcn_s_setprio(1);                                             \
    accl = __builtin_amdgcn_mfma_f32_32x32x16_bf16(paA, ones, accl, 0, 0, 0);  \
    accl = __builtin_amdgcn_mfma_f32_32x32x16_bf16(paB, ones, accl, 0, 0, 0);  \
    {                                                                          \
      const int vcA = (((KSQ0)) * 16 + hi * 8) ^ swL;                          \
      bf16x8 va0 = *(const bf16x8*)(Vc + l31 * 64 + vcA);                      \
      bf16x8 va1 = *(const bf16x8*)(Vc + (32 + l31) * 64 + vcA);               \
      acc0 = __builtin_amdgcn_mfma_f32_32x32x16_bf16(paA, va0, acc0, 0, 0, 0); \
      acc1 = __builtin_amdgcn_mfma_f32_32x32x16_bf16(paA, va1, acc1, 0, 0, 0); \
      const int vcB = (((KSQ0) + 1) * 16 + hi * 8) ^ swL;                      \
      bf16x8 vb0 = *(const bf16x8*)(Vc + l31 * 64 + vcB);                      \
      bf16x8 vb1 = *(const bf16x8*)(Vc + (32 + l31) * 64 + vcB);               \
      acc0 = __builtin_amdgcn_mfma_f32_32x32x16_bf16(paB, vb0, acc0, 0, 0, 0); \
      acc1 = __builtin_amdgcn_mfma_f32_32x32x16_bf16(paB, vb1, acc1, 0, 0, 0); \
    }                                                                          \
    __builtin_amdgcn_s_setprio(0);                                             \
  } while (0)

      KEYBLK(pw0, 0);
      KEYBLK(pw1, 2);
#undef KEYBLK
    }

    if (kt + 1 < ntiles) {
      if (do_stage) {
        asm volatile("s_waitcnt vmcnt(4) lgkmcnt(0)" ::: "memory");
      } else {
        asm volatile("s_waitcnt vmcnt(0) lgkmcnt(0)" ::: "memory");
      }
      barf();
    }
    const int t_ = sc; sc = sn; sn = ss; ss = t_;
  }
#undef STAGE

  const long b = bh >> 4;
  const int h = bh & 15;
#pragma unroll
  for (int r = 0; r < 16; ++r) {
    const float inv = 1.0f / accl[r];
    const int qq = q0 + wave * 32 + ((r & 3) + 8 * (r >> 2)) + 4 * hi;
    ushort* yp = Y + (((b * S_LEN + qq) * NHEAD) + h) * HDIM;
    yp[l31]      = f2b(acc0[r] * inv);
    yp[32 + l31] = f2b(acc1[r] * inv);
  }
}

extern "C" void kernel_launch(void* const* d_in, const int* in_sizes, int n_in,
                              void* d_out, int out_size, void* d_ws, size_t ws_size,
                              hipStream_t stream) {
  const float* x  = (const float*)d_in[0];
  const float* Wq = (const float*)d_in[1];
  const float* Wk = (const float*)d_in[2];
  const float* Wv = (const float*)d_in[3];
  const float* Wo = (const float*)d_in[4];
  const float* bo = (const float*)d_in[5];
  float* out = (float*)d_out;

  const size_t XE = (size_t)8192 * EMB;  // 8388608
  ushort* ws    = (ushort*)d_ws;
  ushort* xb    = ws;
  ushort* Wtqkv = xb + XE;
  ushort* Wto   = Wtqkv + 3 * 1048576;
  ushort* Qb    = Wto + 1048576;
  ushort* Kb    = Qb + XE;
  ushort* Vtb   = Kb + XE;
  ushort* Yb    = xb;  // alias: xb dead after QKV GEMM

  const float SCALE_Q = 1.4426950408889634f / 8.0f;  // log2(e)/sqrt(D)

  prep_kernel<<<dim3(32, 32, 5), 256, 0, stream>>>(
      x, Wq, Wk, Wv, Wo, xb, Wtqkv, Wtqkv + 1048576, Wtqkv + 2097152, Wto, SCALE_Q);

  // QKV: M=8192, N=3072 -> 256x256 tiles, grid 32x12 = 384 blocks
  gemm256_kernel<<<dim3(32, 12), 512, 0, stream>>>(xb, Wtqkv, Qb, Kb, Vtb);
  attn_kernel<<<dim3(64, 16), 256, 0, stream>>>(Qb, Kb, Vtb, Yb);
  // out-proj: M=8192, N=1024 -> 128x256 tiles, grid 64x4 = 256 blocks
  gemm8_kernel<1><<<dim3(64, 4), 512, 0, stream>>>(Yb, Wto, out, bo);
}

// Round 10
// 228.498 us; speedup vs baseline: 1.0156x; 1.0156x over previous
//
#include <hip/hip_runtime.h>

typedef __bf16 bf16x8 __attribute__((ext_vector_type(8)));
typedef float f32x4 __attribute__((ext_vector_type(4)));
typedef float f32x16 __attribute__((ext_vector_type(16)));
typedef unsigned short u16x8 __attribute__((ext_vector_type(8)));
typedef unsigned int u32x4 __attribute__((ext_vector_type(4)));
typedef unsigned int u32x2v __attribute__((ext_vector_type(2)));

#define S_LEN 2048
#define NHEAD 16
#define HDIM  64
#define EMB   1024

__device__ __forceinline__ ushort f2b(float v) {
  union { float f; unsigned u; } x; x.f = v;
  unsigned r = (x.u + 0x7fffu + ((x.u >> 16) & 1u)) >> 16;
  return (ushort)r;
}

// pack two f32 -> u32 of 2 bf16 (truncation)
__device__ __forceinline__ unsigned pk2(float lo, float hi) {
  union { float f; unsigned u; } a, b; a.f = lo; b.f = hi;
  return (b.u & 0xffff0000u) | (a.u >> 16);
}

// async global->LDS, 16B per lane; LDS dest = wave-uniform base + lane*16
typedef const __attribute__((address_space(1))) unsigned int* gp1_t;
typedef __attribute__((address_space(3))) unsigned int* lp3_t;
__device__ __forceinline__ void gld16(const ushort* g, const ushort* l) {
  __builtin_amdgcn_global_load_lds((gp1_t)(unsigned long long)(uintptr_t)g,
                                   (lp3_t)(unsigned int)(uintptr_t)l, 16, 0, 0);
}

__device__ __forceinline__ void barf() {
  asm volatile("" ::: "memory");
  __builtin_amdgcn_s_barrier();
  asm volatile("" ::: "memory");
}

// ---------- fused prep: cast x -> bf16 (z==4) + transpose/cast weights (z<4) ----------
__global__ __launch_bounds__(256) void prep_kernel(
    const float* __restrict__ x, const float* __restrict__ W0,
    const float* __restrict__ W1, const float* __restrict__ W2,
    const float* __restrict__ W3, ushort* __restrict__ xb,
    ushort* __restrict__ Wt0, ushort* __restrict__ Wt1,
    ushort* __restrict__ Wt2, ushort* __restrict__ Wt3, float scale0) {
  const int z = blockIdx.z;
  if (z == 4) {  // x cast: 1024 blocks x 8192 floats
    size_t base = ((size_t)(blockIdx.y * 32 + blockIdx.x)) * 8192 + threadIdx.x * 4;
#pragma unroll
    for (int i = 0; i < 8; ++i) {
      float4 v = *(const float4*)(x + base + i * 1024);
      ushort4 o;
      o.x = f2b(v.x); o.y = f2b(v.y); o.z = f2b(v.z); o.w = f2b(v.w);
      *(ushort4*)(xb + base + i * 1024) = o;
    }
    return;
  }
  __shared__ float t[32][33];
  const float* W = z == 0 ? W0 : (z == 1 ? W1 : (z == 2 ? W2 : W3));
  ushort* Wt = z == 0 ? Wt0 : (z == 1 ? Wt1 : (z == 2 ? Wt2 : Wt3));
  const float scale = z == 0 ? scale0 : 1.0f;
  int k0 = blockIdx.x * 32, n0 = blockIdx.y * 32;
  int c = threadIdx.x & 31, r0 = threadIdx.x >> 5;
#pragma unroll
  for (int i = 0; i < 4; ++i) {
    int r = r0 + i * 8;
    t[r][c] = W[(size_t)(k0 + r) * EMB + n0 + c];
  }
  __syncthreads();
#pragma unroll
  for (int i = 0; i < 4; ++i) {
    int r = r0 + i * 8;
    Wt[(size_t)(n0 + r) * EMB + k0 + c] = f2b(t[c][r] * scale);
  }
}

// ---------------- GEMM v5 128x256 (proven 56us; restored for QKV + out-proj) ----------------
// Swizzled 128B-row LDS (0 bank conflicts), 3-slot ring, counted vmcnt,
// register-double-buffered fragments, ONE barrier per K-tile with
// vmcnt(6)+lgkmcnt(0) BEFORE the barrier (cross-wave staging guarantee).
template <int EPI>
__global__ __launch_bounds__(512, 2) void gemm8_kernel(
    const ushort* __restrict__ A, const ushort* __restrict__ Bt,
    ushort* __restrict__ outQ, ushort* __restrict__ outK, ushort* __restrict__ outVt,
    float* __restrict__ outF, const float* __restrict__ bias) {
  __shared__ ushort lds8[73728];  // 144 KiB
  const int tid = threadIdx.x;
  const int wave = tid >> 6, lane = tid & 63, ln = lane & 15, quad = lane >> 4;
  const int wm = wave >> 2, wn = wave & 3;
  const long m0 = (long)blockIdx.x * 128, n0 = (long)blockIdx.y * 256;
  constexpr int K = EMB, KT = K / 64;  // 16 K-tiles

  const int srow = tid >> 3;
  const int scol = ((tid & 7) ^ (srow & 7)) * 8;
  const ushort* srcA = A + (m0 + srow) * (long)K + scol;
  const ushort* srcB = Bt + (n0 + srow) * (long)K + scol;

#define STG_A(t, s)                                                            \
  do {                                                                         \
    gld16(srcA + (t) * 64,               lds8 + (s) * 8192 + tid * 8);         \
    gld16(srcA + (t) * 64 + 64 * K,      lds8 + (s) * 8192 + 4096 + tid * 8);  \
  } while (0)
#define STG_B(t, s)                                                            \
  do {                                                                         \
    gld16(srcB + (t) * 64,               lds8 + 24576 + (s) * 16384 + tid * 8);         \
    gld16(srcB + (t) * 64 + 64 * K,      lds8 + 24576 + (s) * 16384 + 4096 + tid * 8);  \
    gld16(srcB + (t) * 64 + 128 * K,     lds8 + 24576 + (s) * 16384 + 8192 + tid * 8);  \
    gld16(srcB + (t) * 64 + 192 * K,     lds8 + 24576 + (s) * 16384 + 12288 + tid * 8); \
  } while (0)

  const int sw = (ln & 7) * 8;

#define RD_A(F, kk, s)                                                         \
  do {                                                                         \
    const ushort* p_ = lds8 + (s) * 8192 + (wm * 64 + ln) * 64 +               \
                       (((kk) * 32 + quad * 8) ^ sw);                          \
    F[0] = *(const bf16x8*)p_;                                                 \
    F[1] = *(const bf16x8*)(p_ + 1024);                                        \
    F[2] = *(const bf16x8*)(p_ + 2048);                                        \
    F[3] = *(const bf16x8*)(p_ + 3072);                                        \
  } while (0)
#define RD_B(F, kk, s)                                                         \
  do {                                                                         \
    const ushort* p_ = lds8 + 24576 + (s) * 16384 + (wn * 64 + ln) * 64 +      \
                       (((kk) * 32 + quad * 8) ^ sw);                          \
    F[0] = *(const bf16x8*)p_;                                                 \
    F[1] = *(const bf16x8*)(p_ + 1024);                                        \
    F[2] = *(const bf16x8*)(p_ + 2048);                                        \
    F[3] = *(const bf16x8*)(p_ + 3072);                                        \
  } while (0)

#define MM16(AF, BF)                                                           \
  do {                                                                         \
    __builtin_amdgcn_s_setprio(1);                                             \
    _Pragma("unroll") for (int mt = 0; mt < 4; ++mt)                           \
        _Pragma("unroll") for (int nt = 0; nt < 4; ++nt)                       \
            acc[mt][nt] = __builtin_amdgcn_mfma_f32_16x16x32_bf16(             \
                AF[mt], BF[nt], acc[mt][nt], 0, 0, 0);                         \
    __builtin_amdgcn_s_setprio(0);                                             \
  } while (0)

  f32x4 acc[4][4] = {};
  bf16x8 afP[4], bfP[4], afN[4], bfN[4];

  STG_A(0, 0); STG_B(0, 0);
  STG_A(1, 1); STG_B(1, 1);
  asm volatile("s_waitcnt vmcnt(6)" ::: "memory");
  barf();
  RD_A(afP, 0, 0); RD_B(bfP, 0, 0);

#define TILE_FULL(t, s, s1, s2)                                                \
  do {                                                                         \
    STG_A((t) + 2, s2);                                                        \
    RD_A(afN, 1, s); RD_B(bfN, 1, s);                                          \
    MM16(afP, bfP);                                                            \
    STG_B((t) + 2, s2);                                                        \
    asm volatile("s_waitcnt vmcnt(6) lgkmcnt(0)" ::: "memory");                \
    barf();                                                                    \
    RD_A(afP, 0, s1); RD_B(bfP, 0, s1);                                        \
    MM16(afN, bfN);                                                            \
  } while (0)

  for (int th = 0; th < 12; th += 3) {
    TILE_FULL(th, 0, 1, 2);
    TILE_FULL(th + 1, 1, 2, 0);
    TILE_FULL(th + 2, 2, 0, 1);
  }
  TILE_FULL(12, 0, 1, 2);
  TILE_FULL(13, 1, 2, 0);
  RD_A(afN, 1, 2); RD_B(bfN, 1, 2);
  MM16(afP, bfP);
  asm volatile("s_waitcnt vmcnt(0) lgkmcnt(0)" ::: "memory");
  barf();
  RD_A(afP, 0, 0); RD_B(bfP, 0, 0);
  MM16(afN, bfN);
  RD_A(afN, 1, 0); RD_B(bfN, 1, 0);
  MM16(afP, bfP);
  MM16(afN, bfN);

  if (EPI == 0) {
    const int sel = (int)(n0 >> 10);
    if (sel == 2) {
#pragma unroll
      for (int mt = 0; mt < 4; ++mt) {
        const long mbase = m0 + wm * 64 + mt * 16 + quad * 4;
        const long bb = mbase >> 11, s = mbase & 2047;
#pragma unroll
        for (int nt = 0; nt < 4; ++nt) {
          const int nn = (int)((n0 & 1023) + wn * 64 + nt * 16 + ln);
          const int h = nn >> 6, d = nn & 63;
          uint2 val;
          val.x = (unsigned)f2b(acc[mt][nt][0]) | ((unsigned)f2b(acc[mt][nt][1]) << 16);
          val.y = (unsigned)f2b(acc[mt][nt][2]) | ((unsigned)f2b(acc[mt][nt][3]) << 16);
          *(uint2*)(outVt + (((bb * NHEAD + h) * (long)HDIM + d) * S_LEN) + s) = val;
        }
      }
    } else {
      ushort* dst = sel == 0 ? outQ : outK;
#pragma unroll
      for (int mt = 0; mt < 4; ++mt) {
#pragma unroll
        for (int nt = 0; nt < 4; ++nt) {
          const int nn = (int)((n0 & 1023) + wn * 64 + nt * 16 + ln);
          const int h = nn >> 6, d = nn & 63;
#pragma unroll
          for (int r = 0; r < 4; ++r) {
            const long m = m0 + wm * 64 + mt * 16 + quad * 4 + r;
            const long bb = m >> 11, s = m & 2047;
            dst[(((bb * NHEAD + h) * S_LEN) + s) * HDIM + d] = f2b(acc[mt][nt][r]);
          }
        }
      }
    }
  } else {
#pragma unroll
    for (int mt = 0; mt < 4; ++mt) {
#pragma unroll
      for (int nt = 0; nt < 4; ++nt) {
        const long n = n0 + wn * 64 + nt * 16 + ln;
        const float bv = bias[n];
#pragma unroll
        for (int r = 0; r < 4; ++r) {
          const long m = m0 + wm * 64 + mt * 16 + quad * 4 + r;
          outF[m * (long)EMB + n] = acc[mt][nt][r] + bv;
        }
      }
    }
  }
#undef TILE_FULL
#undef MM16
#undef RD_B
#undef RD_A
#undef STG_B
#undef STG_A
}

// ---------------- flash attention, v9: 40KB LDS -> 4 blocks/CU ----------------
// Q,K: [bh][s][d] bf16 (Q pre-scaled by log2e/8 via Wq).  Vt: [bh][d][s] bf16.
// Y: [b][s][h][d] bf16.
// v9 change: attn is latency-chain-bound (VALUBusy 42 > MfmaUtil 32, neither
// saturated) -> more independent wave-streams per SIMD.  LDS 48->40KB by
// keeping K as a 3-slot ring (stage t+2) and dropping V to a double-buffer
// (stage t+1; ~2300cyc same-tile slack covers landing).  4 blocks/CU = 16
// waves/CU (was 12).  Per tile: issue V(t+1) THEN K(t+2); end-of-tile
// s_waitcnt vmcnt(2) (in-order: leaves only the newest 2 = K(t+2); forces
// V(t+1), K(t+1)) + lgkmcnt(0) BEFORE the single barrier; vmcnt(0) at tails.
// WAR: V(t+1) overwrites V(t-1), K(t+2) overwrites K(t-1) -- both last read
// in tile t-1, lgkm'd before the end-of-(t-1) barrier; stages issue after it.
// v8 kept: swapped-QK 32x32, in-register P, permlane32_swap, setprio.
__global__ __launch_bounds__(256, 4) void attn_kernel(const ushort* __restrict__ Q,
                                                      const ushort* __restrict__ Kg,
                                                      const ushort* __restrict__ Vt,
                                                      ushort* __restrict__ Y) {
  __shared__ alignas(16) ushort Ks[3][4096];  // [slot][key 64][d 64] swizzled
  __shared__ alignas(16) ushort Vs[2][4096];  // [buf][d 64][key 64] swizzled
  const int tid = threadIdx.x;
  const int wave = tid >> 6, lane = tid & 63;
  const int l31 = lane & 31, hi = lane >> 5;
  const int bh = blockIdx.x;
  const int qb = 15 - (int)blockIdx.y;  // LPT: longest q-blocks first
  const int q0 = qb * 128;
  const size_t base = (size_t)bh * S_LEN * HDIM;
  const int ntiles = 2 * qb + 2;

  const u16x8 ob = {0x3F80, 0x3F80, 0x3F80, 0x3F80, 0x3F80, 0x3F80, 0x3F80, 0x3F80};
  const bf16x8 ones = __builtin_bit_cast(bf16x8, ob);

  bf16x8 qf[4];
#pragma unroll
  for (int dsub = 0; dsub < 4; ++dsub)
    qf[dsub] = *(const bf16x8*)(Q + base + (size_t)(q0 + wave * 32 + l31) * HDIM +
                                dsub * 16 + hi * 8);

  f32x16 acc0 = {}, acc1 = {}, accl = {};

  const int srow = tid >> 3;                        // 0..31
  const int scc  = ((tid & 7) ^ (srow & 7)) * 8;    // swizzled ushort col
  const ushort* KgS = Kg + base + (size_t)srow * HDIM + scc;
  const ushort* VgS = Vt + base + (size_t)srow * S_LEN + scc;

#define STAGE_K(t, s)                                                          \
  do {                                                                         \
    const size_t kk_ = (size_t)(t) * 64;                                       \
    gld16(KgS + kk_ * HDIM,               &Ks[s][0] + tid * 8);                \
    gld16(KgS + (kk_ + 32) * HDIM,        &Ks[s][0] + 2048 + tid * 8);         \
  } while (0)
#define STAGE_V(t, b)                                                          \
  do {                                                                         \
    const size_t kk_ = (size_t)(t) * 64;                                       \
    gld16(VgS + kk_,                      &Vs[b][0] + tid * 8);                \
    gld16(VgS + 32 * (size_t)S_LEN + kk_, &Vs[b][0] + 2048 + tid * 8);         \
  } while (0)

  // prologue: K0, V0, K1; wait K0+V0 (leave K1's 2 in flight)
  STAGE_K(0, 0);
  STAGE_V(0, 0);
  STAGE_K(1, 1);
  asm volatile("s_waitcnt vmcnt(2)" ::: "memory");
  barf();

  const int swL = (lane & 7) * 8;   // K/V read swizzle (row&7 == lane&7)
  const int qbase = q0 + wave * 32;
  int sc = 0, sn = 1, ss = 2;       // K ring slots: current / next / stage(t+2)

  for (int kt = 0; kt < ntiles; ++kt) {
    const int k0 = kt * 64;
    const int vbuf = kt & 1;
    const bool stV = (kt + 1 < ntiles);
    const bool stK = (kt + 2 < ntiles);
    if (stV) STAGE_V(kt + 1, vbuf ^ 1);   // issue V BEFORE K (vmcnt order)
    if (stK) STAGE_K(kt + 2, ss);

    const ushort* Kc = &Ks[sc][0];
    const ushort* Vc = &Vs[vbuf][0];

    if (k0 < qbase + 32) {
      f32x16 sT0 = {}, sT1 = {};
      __builtin_amdgcn_s_setprio(1);
#pragma unroll
      for (int dsub = 0; dsub < 4; ++dsub) {
        const int c = (dsub * 16 + hi * 8) ^ swL;
        bf16x8 kf0 = *(const bf16x8*)(Kc + l31 * 64 + c);
        bf16x8 kf1 = *(const bf16x8*)(Kc + (32 + l31) * 64 + c);
        sT0 = __builtin_amdgcn_mfma_f32_32x32x16_bf16(kf0, qf[dsub], sT0, 0, 0, 0);
        sT1 = __builtin_amdgcn_mfma_f32_32x32x16_bf16(kf1, qf[dsub], sT1, 0, 0, 0);
      }
      __builtin_amdgcn_s_setprio(0);

      if (k0 + 63 > qbase) {  // diagonal region: causal mask
        const int rowq = qbase + l31;
#pragma unroll
        for (int r = 0; r < 16; ++r) {
          const int key = k0 + ((r & 3) + 8 * (r >> 2)) + 4 * hi;
          if (key > rowq) sT0[r] = -3.0e38f;
          if (key + 32 > rowq) sT1[r] = -3.0e38f;
        }
      }

      unsigned pw0[8], pw1[8];
#pragma unroll
      for (int i = 0; i < 8; ++i) {
        pw0[i] = pk2(__builtin_amdgcn_exp2f(sT0[2 * i]),
                     __builtin_amdgcn_exp2f(sT0[2 * i + 1]));
        pw1[i] = pk2(__builtin_amdgcn_exp2f(sT1[2 * i]),
                     __builtin_amdgcn_exp2f(sT1[2 * i + 1]));
      }

#define KEYBLK(PW, KSQ0)                                                       \
  do {                                                                         \
    u32x2v r02 = __builtin_amdgcn_permlane32_swap(PW[0], PW[2], false, false); \
    u32x2v r13 = __builtin_amdgcn_permlane32_swap(PW[1], PW[3], false, false); \
    u32x2v r46 = __builtin_amdgcn_permlane32_swap(PW[4], PW[6], false, false); \
    u32x2v r57 = __builtin_amdgcn_permlane32_swap(PW[5], PW[7], false, false); \
    u32x4 fwA, fwB;                                                            \
    fwA[0] = r02[0]; fwA[1] = r13[0]; fwA[2] = r02[1]; fwA[3] = r13[1];        \
    fwB[0] = r46[0]; fwB[1] = r57[0]; fwB[2] = r46[1]; fwB[3] = r57[1];        \
    bf16x8 paA = __builtin_bit_cast(bf16x8, fwA);                              \
    bf16x8 paB = __builtin_bit_cast(bf16x8, fwB);                              \
    __builtin_amdgcn_s_setprio(1);                                             \
    accl = __builtin_amdgcn_mfma_f32_32x32x16_bf16(paA, ones, accl, 0, 0, 0);  \
    accl = __builtin_amdgcn_mfma_f32_32x32x16_bf16(paB, ones, accl, 0, 0, 0);  \
    {                                                                          \
      const int vcA = (((KSQ0)) * 16 + hi * 8) ^ swL;                          \
      bf16x8 va0 = *(const bf16x8*)(Vc + l31 * 64 + vcA);                      \
      bf16x8 va1 = *(const bf16x8*)(Vc + (32 + l31) * 64 + vcA);               \
      acc0 = __builtin_amdgcn_mfma_f32_32x32x16_bf16(paA, va0, acc0, 0, 0, 0); \
      acc1 = __builtin_amdgcn_mfma_f32_32x32x16_bf16(paA, va1, acc1, 0, 0, 0); \
      const int vcB = (((KSQ0) + 1) * 16 + hi * 8) ^ swL;                      \
      bf16x8 vb0 = *(const bf16x8*)(Vc + l31 * 64 + vcB);                      \
      bf16x8 vb1 = *(const bf16x8*)(Vc + (32 + l31) * 64 + vcB);               \
      acc0 = __builtin_amdgcn_mfma_f32_32x32x16_bf16(paB, vb0, acc0, 0, 0, 0); \
      acc1 = __builtin_amdgcn_mfma_f32_32x32x16_bf16(paB, vb1, acc1, 0, 0, 0); \
    }                                                                          \
    __builtin_amdgcn_s_setprio(0);                                             \
  } while (0)

      KEYBLK(pw0, 0);
      KEYBLK(pw1, 2);
#undef KEYBLK
    }

    if (kt + 1 < ntiles) {
      if (stK) {
        asm volatile("s_waitcnt vmcnt(2) lgkmcnt(0)" ::: "memory");
      } else {
        asm volatile("s_waitcnt vmcnt(0) lgkmcnt(0)" ::: "memory");
      }
      barf();
    }
    const int t_ = sc; sc = sn; sn = ss; ss = t_;
  }
#undef STAGE_V
#undef STAGE_K

  const long b = bh >> 4;
  const int h = bh & 15;
#pragma unroll
  for (int r = 0; r < 16; ++r) {
    const float inv = 1.0f / accl[r];
    const int qq = q0 + wave * 32 + ((r & 3) + 8 * (r >> 2)) + 4 * hi;
    ushort* yp = Y + (((b * S_LEN + qq) * NHEAD) + h) * HDIM;
    yp[l31]      = f2b(acc0[r] * inv);
    yp[32 + l31] = f2b(acc1[r] * inv);
  }
}

extern "C" void kernel_launch(void* const* d_in, const int* in_sizes, int n_in,
                              void* d_out, int out_size, void* d_ws, size_t ws_size,
                              hipStream_t stream) {
  const float* x  = (const float*)d_in[0];
  const float* Wq = (const float*)d_in[1];
  const float* Wk = (const float*)d_in[2];
  const float* Wv = (const float*)d_in[3];
  const float* Wo = (const float*)d_in[4];
  const float* bo = (const float*)d_in[5];
  float* out = (float*)d_out;

  const size_t XE = (size_t)8192 * EMB;  // 8388608
  ushort* ws    = (ushort*)d_ws;
  ushort* xb    = ws;
  ushort* Wtqkv = xb + XE;
  ushort* Wto   = Wtqkv + 3 * 1048576;
  ushort* Qb    = Wto + 1048576;
  ushort* Kb    = Qb + XE;
  ushort* Vtb   = Kb + XE;
  ushort* Yb    = xb;  // alias: xb dead after QKV GEMM

  const float SCALE_Q = 1.4426950408889634f / 8.0f;  // log2(e)/sqrt(D)

  prep_kernel<<<dim3(32, 32, 5), 256, 0, stream>>>(
      x, Wq, Wk, Wv, Wo, xb, Wtqkv, Wtqkv + 1048576, Wtqkv + 2097152, Wto, SCALE_Q);

  // QKV: M=8192, N=3072 -> grid 64x12 = 768 blocks = exactly 3 CU-waves
  gemm8_kernel<0><<<dim3(64, 12), 512, 0, stream>>>(xb, Wtqkv, Qb, Kb, Vtb,
                                                    nullptr, nullptr);
  attn_kernel<<<dim3(64, 16), 256, 0, stream>>>(Qb, Kb, Vtb, Yb);
  // out-proj: M=8192, N=1024 -> grid 64x4 = 256 blocks = exactly 1 CU-wave
  gemm8_kernel<1><<<dim3(64, 4), 512, 0, stream>>>(Yb, Wto, nullptr, nullptr,
                                                   nullptr, out, bo);
}

// Round 11
// 223.012 us; speedup vs baseline: 1.0406x; 1.0246x over previous
//
#include <hip/hip_runtime.h>

typedef __bf16 bf16x8 __attribute__((ext_vector_type(8)));
typedef float f32x4 __attribute__((ext_vector_type(4)));
typedef float f32x16 __attribute__((ext_vector_type(16)));
typedef unsigned short u16x8 __attribute__((ext_vector_type(8)));
typedef unsigned int u32x4 __attribute__((ext_vector_type(4)));
typedef unsigned int u32x2v __attribute__((ext_vector_type(2)));

#define S_LEN 2048
#define NHEAD 16
#define HDIM  64
#define EMB   1024

__device__ __forceinline__ ushort f2b(float v) {
  union { float f; unsigned u; } x; x.f = v;
  unsigned r = (x.u + 0x7fffu + ((x.u >> 16) & 1u)) >> 16;
  return (ushort)r;
}

// pack two f32 -> u32 of 2 bf16 (truncation)
__device__ __forceinline__ unsigned pk2(float lo, float hi) {
  union { float f; unsigned u; } a, b; a.f = lo; b.f = hi;
  return (b.u & 0xffff0000u) | (a.u >> 16);
}

// async global->LDS, 16B per lane; LDS dest = wave-uniform base + lane*16
typedef const __attribute__((address_space(1))) unsigned int* gp1_t;
typedef __attribute__((address_space(3))) unsigned int* lp3_t;
__device__ __forceinline__ void gld16(const ushort* g, const ushort* l) {
  __builtin_amdgcn_global_load_lds((gp1_t)(unsigned long long)(uintptr_t)g,
                                   (lp3_t)(unsigned int)(uintptr_t)l, 16, 0, 0);
}

__device__ __forceinline__ void barf() {
  asm volatile("" ::: "memory");
  __builtin_amdgcn_s_barrier();
  asm volatile("" ::: "memory");
}

// ---------- fused prep: cast x -> bf16 (z==4) + transpose/cast weights (z<4) ----------
__global__ __launch_bounds__(256) void prep_kernel(
    const float* __restrict__ x, const float* __restrict__ W0,
    const float* __restrict__ W1, const float* __restrict__ W2,
    const float* __restrict__ W3, ushort* __restrict__ xb,
    ushort* __restrict__ Wt0, ushort* __restrict__ Wt1,
    ushort* __restrict__ Wt2, ushort* __restrict__ Wt3, float scale0) {
  const int z = blockIdx.z;
  if (z == 4) {  // x cast: 1024 blocks x 8192 floats
    size_t base = ((size_t)(blockIdx.y * 32 + blockIdx.x)) * 8192 + threadIdx.x * 4;
#pragma unroll
    for (int i = 0; i < 8; ++i) {
      float4 v = *(const float4*)(x + base + i * 1024);
      ushort4 o;
      o.x = f2b(v.x); o.y = f2b(v.y); o.z = f2b(v.z); o.w = f2b(v.w);
      *(ushort4*)(xb + base + i * 1024) = o;
    }
    return;
  }
  __shared__ float t[32][33];
  const float* W = z == 0 ? W0 : (z == 1 ? W1 : (z == 2 ? W2 : W3));
  ushort* Wt = z == 0 ? Wt0 : (z == 1 ? Wt1 : (z == 2 ? Wt2 : Wt3));
  const float scale = z == 0 ? scale0 : 1.0f;
  int k0 = blockIdx.x * 32, n0 = blockIdx.y * 32;
  int c = threadIdx.x & 31, r0 = threadIdx.x >> 5;
#pragma unroll
  for (int i = 0; i < 4; ++i) {
    int r = r0 + i * 8;
    t[r][c] = W[(size_t)(k0 + r) * EMB + n0 + c];
  }
  __syncthreads();
#pragma unroll
  for (int i = 0; i < 4; ++i) {
    int r = r0 + i * 8;
    Wt[(size_t)(n0 + r) * EMB + k0 + c] = f2b(t[c][r] * scale);
  }
}

// ---------------- GEMM 256x256 v2 (QKV): balanced pipes + v5 overlap ----------------
// r9's 256x256 kernel PASSED but serialized LDS-exec with MFMA (RD -> lgkm
// drain -> MM per phase: tile = 2260+2460 cyc = pipe SUM).  v2 applies the
// v5-proven reg-double-buffer overlap: each 12-read cluster is issued before
// a 32-MFMA cluster and consumed after it -> tile ~= pipe MAX.
//   tile t (buf = t&1):
//     STG_A(t+1,buf^1); STG_B(t+1,buf^1)   // all 8 loads at tile start
//     RD_N(kk1,buf); MM(P=kk0 of t)        // reads overlap MFMA drain
//     s_waitcnt vmcnt(0) lgkmcnt(0); s_barrier   // waits BEFORE barrier
//     RD_P(kk0,buf^1); MM(N=kk1 of t)      // next-tile reads overlap MFMA
// Staging slack: loads issue at tile start, wait is ~1300-1400 cyc later
// (RD_N + MM(P)) -> covers HBM ~900 worst case.  WAR: buf^1 last read before
// the end-of-(t-1) barrier (lgkmcnt(0) enforced); stage issues after it.
// RAW: per-wave vmcnt(0) BEFORE the barrier = cross-wave guarantee.
// Economy vs 128x256: 0.375 ds_reads/MFMA (vs 0.5), staging bytes/FLOP halved.
// Addressing/swizzle/epilogue identical to r9 (harness-verified).
__global__ __launch_bounds__(512, 2) void gemm256_kernel(
    const ushort* __restrict__ A, const ushort* __restrict__ Bt,
    ushort* __restrict__ outQ, ushort* __restrict__ outK,
    ushort* __restrict__ outVt) {
  // A bufs: 2 x [256][64] ushort at 0       (buf b at b*16384)
  // B bufs: 2 x [256][64] ushort at 32768   (buf b at 32768 + b*16384)
  __shared__ ushort lds2[65536];  // 128 KiB
  const int tid = threadIdx.x;
  const int wave = tid >> 6, lane = tid & 63, ln = lane & 15, quad = lane >> 4;
  const int wm = wave >> 2, wn = wave & 3;
  const long m0 = (long)blockIdx.x * 256, n0 = (long)blockIdx.y * 256;
  constexpr int K = EMB, KT = K / 64;  // 16 K-tiles

  const int srow = tid >> 3;                         // 0..63 (+64 per ld)
  const int scol = ((tid & 7) ^ (srow & 7)) * 8;     // swizzled ushort col
  const ushort* srcA = A + (m0 + srow) * (long)K + scol;
  const ushort* srcB = Bt + (n0 + srow) * (long)K + scol;

#define STG_A(t, b)                                                            \
  do {                                                                         \
    _Pragma("unroll") for (int ld = 0; ld < 4; ++ld)                           \
        gld16(srcA + (t) * 64 + ld * 64 * K,                                   \
              lds2 + (b) * 16384 + ld * 4096 + tid * 8);                       \
  } while (0)
#define STG_B(t, b)                                                            \
  do {                                                                         \
    _Pragma("unroll") for (int ld = 0; ld < 4; ++ld)                           \
        gld16(srcB + (t) * 64 + ld * 64 * K,                                   \
              lds2 + 32768 + (b) * 16384 + ld * 4096 + tid * 8);               \
  } while (0)

  const int sw = (ln & 7) * 8;

#define RD_A8(F, kk, b)                                                        \
  do {                                                                         \
    const ushort* p_ = lds2 + (b) * 16384 + (wm * 128 + ln) * 64 +             \
                       (((kk) * 32 + quad * 8) ^ sw);                          \
    _Pragma("unroll") for (int m_ = 0; m_ < 8; ++m_)                           \
        F[m_] = *(const bf16x8*)(p_ + m_ * 1024);                              \
  } while (0)
#define RD_B4(F, kk, b)                                                        \
  do {                                                                         \
    const ushort* p_ = lds2 + 32768 + (b) * 16384 + (wn * 64 + ln) * 64 +      \
                       (((kk) * 32 + quad * 8) ^ sw);                          \
    _Pragma("unroll") for (int n_ = 0; n_ < 4; ++n_)                           \
        F[n_] = *(const bf16x8*)(p_ + n_ * 1024);                              \
  } while (0)

#define MM32(AF, BF)                                                           \
  do {                                                                         \
    __builtin_amdgcn_s_setprio(1);                                             \
    _Pragma("unroll") for (int mt = 0; mt < 8; ++mt)                           \
        _Pragma("unroll") for (int nt = 0; nt < 4; ++nt)                       \
            acc[mt][nt] = __builtin_amdgcn_mfma_f32_16x16x32_bf16(             \
                AF[mt], BF[nt], acc[mt][nt], 0, 0, 0);                         \
    __builtin_amdgcn_s_setprio(0);                                             \
  } while (0)

  f32x4 acc[8][4] = {};
  bf16x8 afP[8], bfP[4], afN[8], bfN[4];

  // prologue: stage tile 0, drain, barrier, preload kk0
  STG_A(0, 0); STG_B(0, 0);
  asm volatile("s_waitcnt vmcnt(0)" ::: "memory");
  barf();
  RD_A8(afP, 0, 0); RD_B4(bfP, 0, 0);

  for (int kt = 0; kt < KT; ++kt) {
    const int bb = kt & 1;
    if (kt + 1 < KT) { STG_A(kt + 1, bb ^ 1); STG_B(kt + 1, bb ^ 1); }
    RD_A8(afN, 1, bb); RD_B4(bfN, 1, bb);
    MM32(afP, bfP);                    // kk0 of t, overlaps RD_N
    if (kt + 1 < KT) {
      asm volatile("s_waitcnt vmcnt(0) lgkmcnt(0)" ::: "memory");
      barf();                          // after: t+1 landed for ALL waves
      RD_A8(afP, 0, bb ^ 1); RD_B4(bfP, 0, bb ^ 1);  // kk0 of t+1
    }
    MM32(afN, bfN);                    // kk1 of t, overlaps RD_P
  }

  // ---- epilogue (r9, harness-verified): Q/K [b,h,s,d]; V^T [b,h,d,s] ----
  const int sel = (int)(n0 >> 10);  // block-uniform (256 | 1024)
  if (sel == 2) {
#pragma unroll
    for (int mt = 0; mt < 8; ++mt) {
      const long mbase = m0 + wm * 128 + mt * 16 + quad * 4;
      const long bb2 = mbase >> 11, s = mbase & 2047;
#pragma unroll
      for (int nt = 0; nt < 4; ++nt) {
        const int nn = (int)((n0 & 1023) + wn * 64 + nt * 16 + ln);
        const int h = nn >> 6, d = nn & 63;
        uint2 val;
        val.x = (unsigned)f2b(acc[mt][nt][0]) | ((unsigned)f2b(acc[mt][nt][1]) << 16);
        val.y = (unsigned)f2b(acc[mt][nt][2]) | ((unsigned)f2b(acc[mt][nt][3]) << 16);
        *(uint2*)(outVt + (((bb2 * NHEAD + h) * (long)HDIM + d) * S_LEN) + s) = val;
      }
    }
  } else {
    ushort* dst = sel == 0 ? outQ : outK;
#pragma unroll
    for (int mt = 0; mt < 8; ++mt) {
#pragma unroll
      for (int nt = 0; nt < 4; ++nt) {
        const int nn = (int)((n0 & 1023) + wn * 64 + nt * 16 + ln);
        const int h = nn >> 6, d = nn & 63;
#pragma unroll
        for (int r = 0; r < 4; ++r) {
          const long m = m0 + wm * 128 + mt * 16 + quad * 4 + r;
          const long bb2 = m >> 11, s = m & 2047;
          dst[(((bb2 * NHEAD + h) * S_LEN) + s) * HDIM + d] = f2b(acc[mt][nt][r]);
        }
      }
    }
  }
#undef MM32
#undef RD_B4
#undef RD_A8
#undef STG_B
#undef STG_A
}

// ---------------- GEMM v5 128x256 (out-proj; proven, unchanged) ----------------
__global__ __launch_bounds__(512, 2) void gemm8_kernel(
    const ushort* __restrict__ A, const ushort* __restrict__ Bt,
    float* __restrict__ outF, const float* __restrict__ bias) {
  __shared__ ushort lds8[73728];  // 144 KiB
  const int tid = threadIdx.x;
  const int wave = tid >> 6, lane = tid & 63, ln = lane & 15, quad = lane >> 4;
  const int wm = wave >> 2, wn = wave & 3;
  const long m0 = (long)blockIdx.x * 128, n0 = (long)blockIdx.y * 256;
  constexpr int K = EMB, KT = K / 64;  // 16 K-tiles

  const int srow = tid >> 3;
  const int scol = ((tid & 7) ^ (srow & 7)) * 8;
  const ushort* srcA = A + (m0 + srow) * (long)K + scol;
  const ushort* srcB = Bt + (n0 + srow) * (long)K + scol;

#define STG_A(t, s)                                                            \
  do {                                                                         \
    gld16(srcA + (t) * 64,               lds8 + (s) * 8192 + tid * 8);         \
    gld16(srcA + (t) * 64 + 64 * K,      lds8 + (s) * 8192 + 4096 + tid * 8);  \
  } while (0)
#define STG_B(t, s)                                                            \
  do {                                                                         \
    gld16(srcB + (t) * 64,               lds8 + 24576 + (s) * 16384 + tid * 8);         \
    gld16(srcB + (t) * 64 + 64 * K,      lds8 + 24576 + (s) * 16384 + 4096 + tid * 8);  \
    gld16(srcB + (t) * 64 + 128 * K,     lds8 + 24576 + (s) * 16384 + 8192 + tid * 8);  \
    gld16(srcB + (t) * 64 + 192 * K,     lds8 + 24576 + (s) * 16384 + 12288 + tid * 8); \
  } while (0)

  const int sw = (ln & 7) * 8;

#define RD_A(F, kk, s)                                                         \
  do {                                                                         \
    const ushort* p_ = lds8 + (s) * 8192 + (wm * 64 + ln) * 64 +               \
                       (((kk) * 32 + quad * 8) ^ sw);                          \
    F[0] = *(const bf16x8*)p_;                                                 \
    F[1] = *(const bf16x8*)(p_ + 1024);                                        \
    F[2] = *(const bf16x8*)(p_ + 2048);                                        \
    F[3] = *(const bf16x8*)(p_ + 3072);                                        \
  } while (0)
#define RD_B(F, kk, s)                                                         \
  do {                                                                         \
    const ushort* p_ = lds8 + 24576 + (s) * 16384 + (wn * 64 + ln) * 64 +      \
                       (((kk) * 32 + quad * 8) ^ sw);                          \
    F[0] = *(const bf16x8*)p_;                                                 \
    F[1] = *(const bf16x8*)(p_ + 1024);                                        \
    F[2] = *(const bf16x8*)(p_ + 2048);                                        \
    F[3] = *(const bf16x8*)(p_ + 3072);                                        \
  } while (0)

#define MM16(AF, BF)                                                           \
  do {                                                                         \
    __builtin_amdgcn_s_setprio(1);                                             \
    _Pragma("unroll") for (int mt = 0; mt < 4; ++mt)                           \
        _Pragma("unroll") for (int nt = 0; nt < 4; ++nt)                       \
            acc[mt][nt] = __builtin_amdgcn_mfma_f32_16x16x32_bf16(             \
                AF[mt], BF[nt], acc[mt][nt], 0, 0, 0);                         \
    __builtin_amdgcn_s_setprio(0);                                             \
  } while (0)

  f32x4 acc[4][4] = {};
  bf16x8 afP[4], bfP[4], afN[4], bfN[4];

  STG_A(0, 0); STG_B(0, 0);
  STG_A(1, 1); STG_B(1, 1);
  asm volatile("s_waitcnt vmcnt(6)" ::: "memory");
  barf();
  RD_A(afP, 0, 0); RD_B(bfP, 0, 0);

#define TILE_FULL(t, s, s1, s2)                                                \
  do {                                                                         \
    STG_A((t) + 2, s2);                                                        \
    RD_A(afN, 1, s); RD_B(bfN, 1, s);                                          \
    MM16(afP, bfP);                                                            \
    STG_B((t) + 2, s2);                                                        \
    asm volatile("s_waitcnt vmcnt(6) lgkmcnt(0)" ::: "memory");                \
    barf();                                                                    \
    RD_A(afP, 0, s1); RD_B(bfP, 0, s1);                                        \
    MM16(afN, bfN);                                                            \
  } while (0)

  for (int th = 0; th < 12; th += 3) {
    TILE_FULL(th, 0, 1, 2);
    TILE_FULL(th + 1, 1, 2, 0);
    TILE_FULL(th + 2, 2, 0, 1);
  }
  TILE_FULL(12, 0, 1, 2);
  TILE_FULL(13, 1, 2, 0);
  RD_A(afN, 1, 2); RD_B(bfN, 1, 2);
  MM16(afP, bfP);
  asm volatile("s_waitcnt vmcnt(0) lgkmcnt(0)" ::: "memory");
  barf();
  RD_A(afP, 0, 0); RD_B(bfP, 0, 0);
  MM16(afN, bfN);
  RD_A(afN, 1, 0); RD_B(bfN, 1, 0);
  MM16(afP, bfP);
  MM16(afN, bfN);

#pragma unroll
  for (int mt = 0; mt < 4; ++mt) {
#pragma unroll
    for (int nt = 0; nt < 4; ++nt) {
      const long n = n0 + wn * 64 + nt * 16 + ln;
      const float bv = bias[n];
#pragma unroll
      for (int r = 0; r < 4; ++r) {
        const long m = m0 + wm * 64 + mt * 16 + quad * 4 + r;
        outF[m * (long)EMB + n] = acc[mt][nt][r] + bv;
      }
    }
  }
#undef TILE_FULL
#undef MM16
#undef RD_B
#undef RD_A
#undef STG_B
#undef STG_A
}

// ---------------- flash attention, v9 (unchanged, passing) ----------------
__global__ __launch_bounds__(256, 4) void attn_kernel(const ushort* __restrict__ Q,
                                                      const ushort* __restrict__ Kg,
                                                      const ushort* __restrict__ Vt,
                                                      ushort* __restrict__ Y) {
  __shared__ alignas(16) ushort Ks[3][4096];  // [slot][key 64][d 64] swizzled
  __shared__ alignas(16) ushort Vs[2][4096];  // [buf][d 64][key 64] swizzled
  const int tid = threadIdx.x;
  const int wave = tid >> 6, lane = tid & 63;
  const int l31 = lane & 31, hi = lane >> 5;
  const int bh = blockIdx.x;
  const int qb = 15 - (int)blockIdx.y;  // LPT: longest q-blocks first
  const int q0 = qb * 128;
  const size_t base = (size_t)bh * S_LEN * HDIM;
  const int ntiles = 2 * qb + 2;

  const u16x8 ob = {0x3F80, 0x3F80, 0x3F80, 0x3F80, 0x3F80, 0x3F80, 0x3F80, 0x3F80};
  const bf16x8 ones = __builtin_bit_cast(bf16x8, ob);

  bf16x8 qf[4];
#pragma unroll
  for (int dsub = 0; dsub < 4; ++dsub)
    qf[dsub] = *(const bf16x8*)(Q + base + (size_t)(q0 + wave * 32 + l31) * HDIM +
                                dsub * 16 + hi * 8);

  f32x16 acc0 = {}, acc1 = {}, accl = {};

  const int srow = tid >> 3;                        // 0..31
  const int scc  = ((tid & 7) ^ (srow & 7)) * 8;    // swizzled ushort col
  const ushort* KgS = Kg + base + (size_t)srow * HDIM + scc;
  const ushort* VgS = Vt + base + (size_t)srow * S_LEN + scc;

#define STAGE_K(t, s)                                                          \
  do {                                                                         \
    const size_t kk_ = (size_t)(t) * 64;                                       \
    gld16(KgS + kk_ * HDIM,               &Ks[s][0] + tid * 8);                \
    gld16(KgS + (kk_ + 32) * HDIM,        &Ks[s][0] + 2048 + tid * 8);         \
  } while (0)
#define STAGE_V(t, b)                                                          \
  do {                                                                         \
    const size_t kk_ = (size_t)(t) * 64;                                       \
    gld16(VgS + kk_,                      &Vs[b][0] + tid * 8);                \
    gld16(VgS + 32 * (size_t)S_LEN + kk_, &Vs[b][0] + 2048 + tid * 8);         \
  } while (0)

  STAGE_K(0, 0);
  STAGE_V(0, 0);
  STAGE_K(1, 1);
  asm volatile("s_waitcnt vmcnt(2)" ::: "memory");
  barf();

  const int swL = (lane & 7) * 8;   // K/V read swizzle (row&7 == lane&7)
  const int qbase = q0 + wave * 32;
  int sc = 0, sn = 1, ss = 2;       // K ring slots: current / next / stage(t+2)

  for (int kt = 0; kt < ntiles; ++kt) {
    const int k0 = kt * 64;
    const int vbuf = kt & 1;
    const bool stV = (kt + 1 < ntiles);
    const bool stK = (kt + 2 < ntiles);
    if (stV) STAGE_V(kt + 1, vbuf ^ 1);   // issue V BEFORE K (vmcnt order)
    if (stK) STAGE_K(kt + 2, ss);

    const ushort* Kc = &Ks[sc][0];
    const ushort* Vc = &Vs[vbuf][0];

    if (k0 < qbase + 32) {
      f32x16 sT0 = {}, sT1 = {};
      __builtin_amdgcn_s_setprio(1);
#pragma unroll
      for (int dsub = 0; dsub < 4; ++dsub) {
        const int c = (dsub * 16 + hi * 8) ^ swL;
        bf16x8 kf0 = *(const bf16x8*)(Kc + l31 * 64 + c);
        bf16x8 kf1 = *(const bf16x8*)(Kc + (32 + l31) * 64 + c);
        sT0 = __builtin_amdgcn_mfma_f32_32x32x16_bf16(kf0, qf[dsub], sT0, 0, 0, 0);
        sT1 = __builtin_amdgcn_mfma_f32_32x32x16_bf16(kf1, qf[dsub], sT1, 0, 0, 0);
      }
      __builtin_amdgcn_s_setprio(0);

      if (k0 + 63 > qbase) {  // diagonal region: causal mask
        const int rowq = qbase + l31;
#pragma unroll
        for (int r = 0; r < 16; ++r) {
          const int key = k0 + ((r & 3) + 8 * (r >> 2)) + 4 * hi;
          if (key > rowq) sT0[r] = -3.0e38f;
          if (key + 32 > rowq) sT1[r] = -3.0e38f;
        }
      }

      unsigned pw0[8], pw1[8];
#pragma unroll
      for (int i = 0; i < 8; ++i) {
        pw0[i] = pk2(__builtin_amdgcn_exp2f(sT0[2 * i]),
                     __builtin_amdgcn_exp2f(sT0[2 * i + 1]));
        pw1[i] = pk2(__builtin_amdgcn_exp2f(sT1[2 * i]),
                     __builtin_amdgcn_exp2f(sT1[2 * i + 1]));
      }

#define KEYBLK(PW, KSQ0)                                                       \
  do {                                                                         \
    u32x2v r02 = __builtin_amdgcn_permlane32_swap(PW[0], PW[2], false, false); \
    u32x2v r13 = __builtin_amdgcn_permlane32_swap(PW[1], PW[3], false, false); \
    u32x2v r46 = __builtin_amdgcn_permlane32_swap(PW[4], PW[6], false, false); \
    u32x2v r57 = __builtin_amdgcn_permlane32_swap(PW[5], PW[7], false, false); \
    u32x4 fwA, fwB;                                                            \
    fwA[0] = r02[0]; fwA[1] = r13[0]; fwA[2] = r02[1]; fwA[3] = r13[1];        \
    fwB[0] = r46[0]; fwB[1] = r57[0]; fwB[2] = r46[1]; fwB[3] = r57[1];        \
    bf16x8 paA = __builtin_bit_cast(bf16x8, fwA);                              \
    bf16x8 paB = __builtin_bit_cast(bf16x8, fwB);                              \
    __builtin_amdgcn_s_setprio(1);                                             \
    accl = __builtin_amdgcn_mfma_f32_32x32x16_bf16(paA, ones, accl, 0, 0, 0);  \
    accl = __builtin_amdgcn_mfma_f32_32x32x16_bf16(paB, ones, accl, 0, 0, 0);  \
    {                                                                          \
      const int vcA = (((KSQ0)) * 16 + hi * 8) ^ swL;                          \
      bf16x8 va0 = *(const bf16x8*)(Vc + l31 * 64 + vcA);                      \
      bf16x8 va1 = *(const bf16x8*)(Vc + (32 + l31) * 64 + vcA);               \
      acc0 = __builtin_amdgcn_mfma_f32_32x32x16_bf16(paA, va0, acc0, 0, 0, 0); \
      acc1 = __builtin_amdgcn_mfma_f32_32x32x16_bf16(paA, va1, acc1, 0, 0, 0); \
      const int vcB = (((KSQ0) + 1) * 16 + hi * 8) ^ swL;                      \
      bf16x8 vb0 = *(const bf16x8*)(Vc + l31 * 64 + vcB);                      \
      bf16x8 vb1 = *(const bf16x8*)(Vc + (32 + l31) * 64 + vcB);               \
      acc0 = __builtin_amdgcn_mfma_f32_32x32x16_bf16(paB, vb0, acc0, 0, 0, 0); \
      acc1 = __builtin_amdgcn_mfma_f32_32x32x16_bf16(paB, vb1, acc1, 0, 0, 0); \
    }                                                                          \
    __builtin_amdgcn_s_setprio(0);                                             \
  } while (0)

      KEYBLK(pw0, 0);
      KEYBLK(pw1, 2);
#undef KEYBLK
    }

    if (kt + 1 < ntiles) {
      if (stK) {
        asm volatile("s_waitcnt vmcnt(2) lgkmcnt(0)" ::: "memory");
      } else {
        asm volatile("s_waitcnt vmcnt(0) lgkmcnt(0)" ::: "memory");
      }
      barf();
    }
    const int t_ = sc; sc = sn; sn = ss; ss = t_;
  }
#undef STAGE_V
#undef STAGE_K

  const long b = bh >> 4;
  const int h = bh & 15;
#pragma unroll
  for (int r = 0; r < 16; ++r) {
    const float inv = 1.0f / accl[r];
    const int qq = q0 + wave * 32 + ((r & 3) + 8 * (r >> 2)) + 4 * hi;
    ushort* yp = Y + (((b * S_LEN + qq) * NHEAD) + h) * HDIM;
    yp[l31]      = f2b(acc0[r] * inv);
    yp[32 + l31] = f2b(acc1[r] * inv);
  }
}

extern "C" void kernel_launch(void* const* d_in, const int* in_sizes, int n_in,
                              void* d_out, int out_size, void* d_ws, size_t ws_size,
                              hipStream_t stream) {
  const float* x  = (const float*)d_in[0];
  const float* Wq = (const float*)d_in[1];
  const float* Wk = (const float*)d_in[2];
  const float* Wv = (const float*)d_in[3];
  const float* Wo = (const float*)d_in[4];
  const float* bo = (const float*)d_in[5];
  float* out = (float*)d_out;

  const size_t XE = (size_t)8192 * EMB;  // 8388608
  ushort* ws    = (ushort*)d_ws;
  ushort* xb    = ws;
  ushort* Wtqkv = xb + XE;
  ushort* Wto   = Wtqkv + 3 * 1048576;
  ushort* Qb    = Wto + 1048576;
  ushort* Kb    = Qb + XE;
  ushort* Vtb   = Kb + XE;
  ushort* Yb    = xb;  // alias: xb dead after QKV GEMM

  const float SCALE_Q = 1.4426950408889634f / 8.0f;  // log2(e)/sqrt(D)

  prep_kernel<<<dim3(32, 32, 5), 256, 0, stream>>>(
      x, Wq, Wk, Wv, Wo, xb, Wtqkv, Wtqkv + 1048576, Wtqkv + 2097152, Wto, SCALE_Q);

  // QKV: M=8192, N=3072 -> 256x256 tiles, grid 32x12 = 384 blocks
  gemm256_kernel<<<dim3(32, 12), 512, 0, stream>>>(xb, Wtqkv, Qb, Kb, Vtb);
  attn_kernel<<<dim3(64, 16), 256, 0, stream>>>(Qb, Kb, Vtb, Yb);
  // out-proj: M=8192, N=1024 -> 128x256 tiles, grid 64x4 = 256 blocks
  gemm8_kernel<<<dim3(64, 4), 512, 0, stream>>>(Yb, Wto, out, bo);
}